// Round 2
// baseline (500.438 us; speedup 1.0000x reference)
//
#include <hip/hip_runtime.h>
#include <hip/hip_bf16.h>

typedef __attribute__((ext_vector_type(8))) short short8;
typedef __attribute__((ext_vector_type(4))) float f32x4;
typedef __attribute__((ext_vector_type(16))) float f32x16;
typedef __attribute__((ext_vector_type(4))) unsigned int u32x4;

#define NB 8
#define NC 256
#define NNN 4096
#define L2E 1.44269504088896f

__device__ __forceinline__ ushort f2bf(float f) {
  __hip_bfloat16 h = __float2bfloat16(f);
  return *reinterpret_cast<ushort*>(&h);
}
__device__ __forceinline__ unsigned pack2(float a, float b) {
  return (unsigned)f2bf(a) | ((unsigned)f2bf(b) << 16);
}

// fT[b][n][c] = bf16(x[b][c][n])
__global__ __launch_bounds__(256) void prep_kernel(const float* __restrict__ x,
                                                   ushort* __restrict__ fT) {
  __shared__ float tile[32][33];
  const int tx = threadIdx.x, ty = threadIdx.y;
  const int n0 = blockIdx.x * 32, c0 = blockIdx.y * 32, b = blockIdx.z;
#pragma unroll
  for (int k = 0; k < 4; ++k) {
    tile[ty + 8 * k][tx] =
        x[((size_t)(b * NC + c0 + ty + 8 * k)) * NNN + n0 + tx];
  }
  __syncthreads();
#pragma unroll
  for (int k = 0; k < 4; ++k) {
    int n = n0 + ty + 8 * k;
    fT[((size_t)(b * NNN + n)) * NC + c0 + tx] = f2bf(tile[tx][ty + 8 * k]);
  }
}

// Flash attention, 32x32x16 bf16 MFMA, swapped QK^T, in-register softmax.
// Block: 4 waves x 32 query rows = 128 rows. Grid: 8 batches x 32 tiles = 256.
__global__ __launch_bounds__(256, 1) void attn_kernel(
    const float* __restrict__ x, const ushort* __restrict__ fT,
    const float* __restrict__ gamma, float* __restrict__ out) {
  // Kt [64 m][256 c] bf16 @0 (32KB, 512B rows, 16B-slot XOR swizzle by m&7)
  // Vt [256 c][64 m] bf16 @32768 (32KB, 128B rows, XOR swizzle by c&7)
  // epilogue overlay: float ot[4][32][129]  (66048 B total)
  __shared__ __align__(16) char smem[66048];

  const int tid = threadIdx.x;
  const int w = tid >> 6;
  const int l = tid & 63;
  const int l31 = l & 31;
  const int h = l >> 5;
  const int b = blockIdx.x & 7;             // batch -> XCD
  const int gn0 = (blockIdx.x >> 3) * 128;  // query-row base of block
  const int n0w = gn0 + w * 32;             // this wave's 32 rows

  const ushort* fTb = fT + (size_t)b * NNN * NC;
  const float* xb = x + (size_t)b * NC * NNN;

  // Q fragments (B operand): col n = l31 -> row n0w+l31; k = kc*16+8h+j
  short8 q[16];
  {
    const ushort* qp = fTb + (size_t)(n0w + l31) * NC + 8 * h;
#pragma unroll
    for (int kc = 0; kc < 16; ++kc) q[kc] = *(const short8*)(qp + kc * 16);
  }

  f32x16 o[8];
#pragma unroll
  for (int cf = 0; cf < 8; ++cf)
#pragma unroll
    for (int r = 0; r < 16; ++r) o[cf][r] = 0.f;
  float m_run = -3.0e38f, l_run = 0.f;

  // staging prefetch registers (T14)
  short8 kreg[8];
  f32x4 vreg[16];
  const int km = tid & 63;  // K row staged by this thread
#pragma unroll
  for (int k = 0; k < 8; ++k)
    kreg[k] = *(const short8*)(fTb + (size_t)km * NC + (w + 4 * k) * 8);
#pragma unroll
  for (int k = 0; k < 16; ++k)
    vreg[k] = *(const f32x4*)(xb + (size_t)tid * NNN + 4 * k);

  for (int t = 0; t < 64; ++t) {
    // ---- stage tile t from regs into LDS (swizzled, conflict-free) ----
#pragma unroll
    for (int k = 0; k < 8; ++k) {
      const int byte = ((w + 4 * k) * 16) ^ ((km & 7) << 4);
      *(short8*)(smem + km * 512 + byte) = kreg[k];
    }
#pragma unroll
    for (int k = 0; k < 8; ++k) {
      f32x4 a0 = vreg[2 * k], a1 = vreg[2 * k + 1];
      short8 wv;
      wv[0] = (short)f2bf(a0[0]); wv[1] = (short)f2bf(a0[1]);
      wv[2] = (short)f2bf(a0[2]); wv[3] = (short)f2bf(a0[3]);
      wv[4] = (short)f2bf(a1[0]); wv[5] = (short)f2bf(a1[1]);
      wv[6] = (short)f2bf(a1[2]); wv[7] = (short)f2bf(a1[3]);
      const int byte = (k * 16) ^ ((tid & 7) << 4);
      *(short8*)(smem + 32768 + tid * 128 + byte) = wv;
    }
    __syncthreads();

    // ---- prefetch tile t+1 into regs (latency hides under compute) ----
    if (t < 63) {
      const int m0 = (t + 1) * 64;
#pragma unroll
      for (int k = 0; k < 8; ++k)
        kreg[k] =
            *(const short8*)(fTb + (size_t)(m0 + km) * NC + (w + 4 * k) * 8);
#pragma unroll
      for (int k = 0; k < 16; ++k)
        vreg[k] = *(const f32x4*)(xb + (size_t)tid * NNN + m0 + 4 * k);
    }

    // ---- S^T = K * Q^T : A = K rows m, B = Q cols n ----
    f32x16 s0, s1;
#pragma unroll
    for (int r = 0; r < 16; ++r) { s0[r] = 0.f; s1[r] = 0.f; }
#pragma unroll
    for (int kc = 0; kc < 16; ++kc) {
      const int bb = (kc * 32 + 16 * h) ^ ((l31 & 7) << 4);
      short8 ka0 = *(const short8*)(smem + l31 * 512 + bb);
      short8 ka1 = *(const short8*)(smem + (32 + l31) * 512 + bb);
      s0 = __builtin_amdgcn_mfma_f32_32x32x16_bf16(ka0, q[kc], s0, 0, 0, 0);
      s1 = __builtin_amdgcn_mfma_f32_32x32x16_bf16(ka1, q[kc], s1, 0, 0, 0);
    }

    // ---- online softmax; lane owns col n=l31, m values in regs ----
    float tm = s0[0];
#pragma unroll
    for (int r = 1; r < 16; ++r) tm = fmaxf(tm, s0[r]);
#pragma unroll
    for (int r = 0; r < 16; ++r) tm = fmaxf(tm, s1[r]);
    tm = fmaxf(tm, __shfl_xor(tm, 32));

    if (__any(tm > m_run + 8.f)) {  // T13 defer-max
      const float mnew = fmaxf(m_run, tm);
      const float alpha = exp2f((m_run - mnew) * L2E);
      m_run = mnew;
      l_run *= alpha;
      float ar[16];
#pragma unroll
      for (int r = 0; r < 16; ++r)
        ar[r] = __shfl(alpha, (r & 3) + 8 * (r >> 2) + 4 * h);
#pragma unroll
      for (int cf = 0; cf < 8; ++cf)
#pragma unroll
        for (int r = 0; r < 16; ++r) o[cf][r] *= ar[r];
    }

    float rsum = 0.f;
#pragma unroll
    for (int r = 0; r < 16; ++r) {
      float p = exp2f((s0[r] - m_run) * L2E); s0[r] = p; rsum += p;
    }
#pragma unroll
    for (int r = 0; r < 16; ++r) {
      float p = exp2f((s1[r] - m_run) * L2E); s1[r] = p; rsum += p;
    }
    rsum += __shfl_xor(rsum, 32);
    l_run += rsum;

    // ---- pack P to bf16 dwords; m-pair of d[k] = 8*(k>>1)+2*(k&1)+4h ----
    unsigned d0[8], d1[8];
#pragma unroll
    for (int k = 0; k < 8; ++k) {
      const int rg = 4 * (k >> 1) + 2 * (k & 1);
      d0[k] = pack2(s0[rg], s0[rg + 1]);
      d1[k] = pack2(s1[rg], s1[rg + 1]);
    }
    // exchange complementary m-pairs with partner half (lane ^ 32)
    unsigned x0[4], x1[4];
#pragma unroll
    for (int j = 0; j < 4; ++j) {
      const int iH1 = (j < 2) ? j : j + 2;      // what h==1 sends
      const int iH0 = (j < 2) ? j + 2 : j + 4;  // what h==0 sends
      unsigned s0v = h ? d0[iH1] : d0[iH0];
      unsigned s1v = h ? d1[iH1] : d1[iH0];
      x0[j] = (unsigned)__shfl_xor((int)s0v, 32);
      x1[j] = (unsigned)__shfl_xor((int)s1v, 32);
    }

    // ---- O += P * V ----
#pragma unroll
    for (int ks = 0; ks < 4; ++ks) {
      const int e = ks & 1;
      unsigned fa0, fa1, fa2, fa3;
      if (ks < 2) {
        fa0 = h ? x0[2 * e] : d0[4 * e];
        fa1 = h ? x0[2 * e + 1] : d0[4 * e + 1];
        fa2 = h ? d0[4 * e + 2] : x0[2 * e];
        fa3 = h ? d0[4 * e + 3] : x0[2 * e + 1];
      } else {
        fa0 = h ? x1[2 * e] : d1[4 * e];
        fa1 = h ? x1[2 * e + 1] : d1[4 * e + 1];
        fa2 = h ? d1[4 * e + 2] : x1[2 * e];
        fa3 = h ? d1[4 * e + 3] : x1[2 * e + 1];
      }
      u32x4 fu = {fa0, fa1, fa2, fa3};
      short8 pa = __builtin_bit_cast(short8, fu);
#pragma unroll
      for (int cf = 0; cf < 8; ++cf) {
        const int c = cf * 32 + l31;
        const int byte = (ks * 32 + 16 * h) ^ ((c & 7) << 4);
        short8 vb = *(const short8*)(smem + 32768 + c * 128 + byte);
        o[cf] = __builtin_amdgcn_mfma_f32_32x32x16_bf16(pa, vb, o[cf], 0, 0, 0);
      }
    }
    __syncthreads();
  }

  // ---- epilogue: normalize, transpose via LDS (overlay), coalesced store ----
  const float linv = 1.0f / l_run;
  float lr[16];
#pragma unroll
  for (int r = 0; r < 16; ++r)
    lr[r] = __shfl(linv, (r & 3) + 8 * (r >> 2) + 4 * h);
  const float gam = gamma[0];
  float* ot = (float*)smem + w * (32 * 129);
#pragma unroll
  for (int pass = 0; pass < 2; ++pass) {
#pragma unroll
    for (int cf = 0; cf < 4; ++cf) {
      const int cfg = pass * 4 + cf;
#pragma unroll
      for (int r = 0; r < 16; ++r) {
        const int nr = (r & 3) + 8 * (r >> 2) + 4 * h;
        ot[nr * 129 + cf * 32 + l31] = o[cfg][r] * lr[r];
      }
    }
    __syncthreads();
#pragma unroll 8
    for (int i = 0; i < 64; ++i) {
      const int cl = 2 * i + h;
      const float ov = ot[l31 * 129 + cl];
      const size_t gi =
          ((size_t)(b * NC + pass * 128 + cl)) * NNN + n0w + l31;
      out[gi] = gam * ov + x[gi];
    }
    __syncthreads();
  }
}

extern "C" void kernel_launch(void* const* d_in, const int* in_sizes, int n_in,
                              void* d_out, int out_size, void* d_ws,
                              size_t ws_size, hipStream_t stream) {
  const float* x = (const float*)d_in[0];
  const float* gamma = (const float*)d_in[1];
  float* out = (float*)d_out;
  ushort* fT = (ushort*)d_ws;  // 8*4096*256*2 = 16.78 MB

  dim3 pg(NNN / 32, NC / 32, NB);
  dim3 pb(32, 8, 1);
  prep_kernel<<<pg, pb, 0, stream>>>(x, fT);

  attn_kernel<<<dim3(256), dim3(256), 0, stream>>>(x, fT, gamma, out);
}

// Round 4
// 245.152 us; speedup vs baseline: 2.0413x; 2.0413x over previous
//
#include <hip/hip_runtime.h>
#include <hip/hip_bf16.h>

typedef __attribute__((ext_vector_type(8))) short short8;
typedef __attribute__((ext_vector_type(4))) float f32x4;
typedef __attribute__((ext_vector_type(16))) float f32x16;
typedef __attribute__((ext_vector_type(4))) unsigned int u32x4;

#define NB 8
#define NC 256
#define NNN 4096
#define L2E 1.44269504088896f

__device__ __forceinline__ ushort f2bf(float f) {
  __hip_bfloat16 h = __float2bfloat16(f);
  return *reinterpret_cast<ushort*>(&h);
}
__device__ __forceinline__ unsigned pack2(float a, float b) {
  return (unsigned)f2bf(a) | ((unsigned)f2bf(b) << 16);
}
__device__ __forceinline__ void gload16(const void* g, void* l) {
  __builtin_amdgcn_global_load_lds(
      (const __attribute__((address_space(1))) void*)g,
      (__attribute__((address_space(3))) void*)l, 16, 0, 0);
}

// fTs[b][n][c ^ ((n&7)<<3)] = bf16(x[b][c][n])   (chunk-swizzled rows, 512B)
__global__ __launch_bounds__(256) void prep_T(const float* __restrict__ x,
                                              ushort* __restrict__ fTs) {
  __shared__ float tile[32][33];
  const int tx = threadIdx.x, ty = threadIdx.y;
  const int n0 = blockIdx.x * 32, c0 = blockIdx.y * 32, b = blockIdx.z;
#pragma unroll
  for (int k = 0; k < 4; ++k) {
    tile[ty + 8 * k][tx] =
        x[((size_t)(b * NC + c0 + ty + 8 * k)) * NNN + n0 + tx];
  }
  __syncthreads();
#pragma unroll
  for (int k = 0; k < 4; ++k) {
    const int n = n0 + ty + 8 * k;
    const int c = c0 + tx;
    fTs[(size_t)(b * NNN + n) * NC + (c ^ ((n & 7) << 3))] =
        f2bf(tile[tx][ty + 8 * k]);
  }
}

// fVs[b][c][64t + (mm ^ ((c&7)<<3))] = bf16(x[b][c][64t+mm])
__global__ __launch_bounds__(256) void prep_V(const float* __restrict__ x,
                                              ushort* __restrict__ fVs) {
  const size_t ci = (size_t)blockIdx.x * 256 + threadIdx.x;  // 1M chunks
  const int p = (int)(ci & 511);
  const int c = (int)((ci >> 9) & 255);
  const int b = (int)(ci >> 17);
  const int lp = (p & ~7) | ((p & 7) ^ (c & 7));  // logical chunk
  const float* src = x + ((size_t)(b * NC + c)) * NNN + lp * 8;
  f32x4 a0 = *(const f32x4*)src;
  f32x4 a1 = *(const f32x4*)(src + 4);
  short8 w;
  w[0] = (short)f2bf(a0[0]); w[1] = (short)f2bf(a0[1]);
  w[2] = (short)f2bf(a0[2]); w[3] = (short)f2bf(a0[3]);
  w[4] = (short)f2bf(a1[0]); w[5] = (short)f2bf(a1[1]);
  w[6] = (short)f2bf(a1[2]); w[7] = (short)f2bf(a1[3]);
  *(short8*)(fVs + ((size_t)(b * NC + c)) * NNN + p * 8) = w;
}

// Flash attention, 32x32x16 bf16 MFMA, swapped QK^T, in-register softmax.
// 4 waves x 32 query rows = 128 rows/block. Grid 256 (1/CU).
// LDS: double-buffered {Kt 32KB + Vt 32KB} = 128KB. global_load_lds staging.
__global__ __launch_bounds__(256, 1) void attn_kernel(
    const float* __restrict__ x, const ushort* __restrict__ fTs,
    const ushort* __restrict__ fVs, const float* __restrict__ gamma,
    float* __restrict__ out) {
  __shared__ __align__(16) char smem[131072];

  const int tid = threadIdx.x;
  const int w = tid >> 6;
  const int l = tid & 63;
  const int l31 = l & 31;
  const int h = l >> 5;
  const int b = blockIdx.x & 7;             // batch -> XCD
  const int gn0 = (blockIdx.x >> 3) * 128;  // query-row base of block
  const int n0w = gn0 + w * 32;             // this wave's 32 rows

  const char* fTb = (const char*)(fTs + (size_t)b * NNN * NC);
  const char* fVb = (const char*)(fVs + (size_t)b * NNN * NC);

  // Q fragments (B operand): col n = l31 -> row n0w+l31; k = kc*16+8h+j
  short8 q[16];
  {
    const int n = n0w + l31;
    const char* qrow = fTb + (size_t)n * 512;
    const int sw = (n & 7) << 4;
#pragma unroll
    for (int kc = 0; kc < 16; ++kc)
      q[kc] = *(const short8*)(qrow + ((kc * 32 + 16 * h) ^ sw));
  }

  f32x16 o[8];
#pragma unroll
  for (int cf = 0; cf < 8; ++cf)
#pragma unroll
    for (int r = 0; r < 16; ++r) o[cf][r] = 0.f;
  float m_run = -3.0e38f, l_run = 0.f;

  // staging source addresses (per-lane), dest is linear per wave
  const int krow = w * 16 + (l >> 5);
  const char* gK0 = fTb + (size_t)krow * 512 + (l & 31) * 16;
  const int vrow = w * 64 + (l >> 3);
  const char* gV0 = fVb + (size_t)vrow * 8192 + (l & 7) * 16;

  // prologue: stage tile 0 into buffer 0 (K @0, V @32768)
#pragma unroll
  for (int i = 0; i < 8; ++i)
    gload16(gK0 + (size_t)i * 1024, smem + w * 8192 + i * 1024);
#pragma unroll
  for (int i = 0; i < 8; ++i)
    gload16(gV0 + (size_t)i * 65536, smem + 32768 + w * 8192 + i * 1024);
  __syncthreads();

  for (int t = 0; t < 64; ++t) {
    const int p = t & 1;
    char* bufC = smem + p * 65536;         // current buffer base
    char* bufN = smem + (p ^ 1) * 65536;   // next buffer base
    // issue next tile's staging; completes during this tile's compute
    if (t < 63) {
      const size_t kOff = (size_t)(t + 1) * 64 * 512;  // m0*512 bytes
      const size_t vOff = (size_t)(t + 1) * 128;       // m0*2 bytes
#pragma unroll
      for (int i = 0; i < 8; ++i)
        gload16(gK0 + kOff + (size_t)i * 1024, bufN + w * 8192 + i * 1024);
#pragma unroll
      for (int i = 0; i < 8; ++i)
        gload16(gV0 + vOff + (size_t)i * 65536,
                bufN + 32768 + w * 8192 + i * 1024);
    }

    // ---- S^T = K * Q^T : A = K rows m (LDS), B = Q cols n (regs) ----
    const char* Kp = bufC;
    const char* Vp = bufC + 32768;
    f32x16 s0, s1;
#pragma unroll
    for (int r = 0; r < 16; ++r) { s0[r] = 0.f; s1[r] = 0.f; }
#pragma unroll
    for (int kc = 0; kc < 16; ++kc) {
      const int bb = (kc * 32 + 16 * h) ^ ((l31 & 7) << 4);
      short8 ka0 = *(const short8*)(Kp + l31 * 512 + bb);
      short8 ka1 = *(const short8*)(Kp + (32 + l31) * 512 + bb);
      s0 = __builtin_amdgcn_mfma_f32_32x32x16_bf16(ka0, q[kc], s0, 0, 0, 0);
      s1 = __builtin_amdgcn_mfma_f32_32x32x16_bf16(ka1, q[kc], s1, 0, 0, 0);
    }

    // ---- online softmax; lane owns col n = l31 ----
    float tm = s0[0];
#pragma unroll
    for (int r = 1; r < 16; ++r) tm = fmaxf(tm, s0[r]);
#pragma unroll
    for (int r = 0; r < 16; ++r) tm = fmaxf(tm, s1[r]);
    tm = fmaxf(tm, __shfl_xor(tm, 32));

    if (__any(tm > m_run + 8.f)) {  // T13 defer-max
      const float mnew = fmaxf(m_run, tm);
      const float alpha = exp2f((m_run - mnew) * L2E);
      m_run = mnew;
      l_run *= alpha;
      float ar[16];
#pragma unroll
      for (int r = 0; r < 16; ++r)
        ar[r] = __shfl(alpha, (r & 3) + 8 * (r >> 2) + 4 * h);
#pragma unroll
      for (int cf = 0; cf < 8; ++cf)
#pragma unroll
        for (int r = 0; r < 16; ++r) o[cf][r] *= ar[r];
    }

    float rsum = 0.f;
#pragma unroll
    for (int r = 0; r < 16; ++r) {
      float pv = exp2f((s0[r] - m_run) * L2E); s0[r] = pv; rsum += pv;
    }
#pragma unroll
    for (int r = 0; r < 16; ++r) {
      float pv = exp2f((s1[r] - m_run) * L2E); s1[r] = pv; rsum += pv;
    }
    rsum += __shfl_xor(rsum, 32);
    l_run += rsum;

    // ---- pack P to bf16 dwords; m-pair of d[k] = 8*(k>>1)+2*(k&1)+4h ----
    unsigned d0[8], d1[8];
#pragma unroll
    for (int k = 0; k < 8; ++k) {
      const int rg = 4 * (k >> 1) + 2 * (k & 1);
      d0[k] = pack2(s0[rg], s0[rg + 1]);
      d1[k] = pack2(s1[rg], s1[rg + 1]);
    }
    // exchange complementary m-pairs with partner half (lane ^ 32)
    unsigned x0[4], x1[4];
#pragma unroll
    for (int j = 0; j < 4; ++j) {
      const int iH1 = (j < 2) ? j : j + 2;      // what h==1 sends
      const int iH0 = (j < 2) ? j + 2 : j + 4;  // what h==0 sends
      unsigned s0v = h ? d0[iH1] : d0[iH0];
      unsigned s1v = h ? d1[iH1] : d1[iH0];
      x0[j] = (unsigned)__shfl_xor((int)s0v, 32);
      x1[j] = (unsigned)__shfl_xor((int)s1v, 32);
    }

    // ---- O += P * V ----
#pragma unroll
    for (int ks = 0; ks < 4; ++ks) {
      const int e = ks & 1;
      unsigned fa0, fa1, fa2, fa3;
      if (ks < 2) {
        fa0 = h ? x0[2 * e] : d0[4 * e];
        fa1 = h ? x0[2 * e + 1] : d0[4 * e + 1];
        fa2 = h ? d0[4 * e + 2] : x0[2 * e];
        fa3 = h ? d0[4 * e + 3] : x0[2 * e + 1];
      } else {
        fa0 = h ? x1[2 * e] : d1[4 * e];
        fa1 = h ? x1[2 * e + 1] : d1[4 * e + 1];
        fa2 = h ? d1[4 * e + 2] : x1[2 * e];
        fa3 = h ? d1[4 * e + 3] : x1[2 * e + 1];
      }
      u32x4 fu = {fa0, fa1, fa2, fa3};
      short8 pa = __builtin_bit_cast(short8, fu);
#pragma unroll
      for (int cf = 0; cf < 8; ++cf) {
        const int c = cf * 32 + l31;
        const int byte = (ks * 32 + 16 * h) ^ ((c & 7) << 4);
        short8 vb = *(const short8*)(Vp + c * 128 + byte);
        o[cf] = __builtin_amdgcn_mfma_f32_32x32x16_bf16(pa, vb, o[cf], 0, 0, 0);
      }
    }
    __syncthreads();
  }

  // ---- epilogue: normalize, transpose via LDS (overlay), coalesced store ----
  const float linv = 1.0f / l_run;
  float lr[16];
#pragma unroll
  for (int r = 0; r < 16; ++r)
    lr[r] = __shfl(linv, (r & 3) + 8 * (r >> 2) + 4 * h);
  const float gam = gamma[0];
  float* ot = (float*)smem + w * (32 * 129);
#pragma unroll
  for (int pass = 0; pass < 2; ++pass) {
#pragma unroll
    for (int cf = 0; cf < 4; ++cf) {
      const int cfg = pass * 4 + cf;
#pragma unroll
      for (int r = 0; r < 16; ++r) {
        const int nr = (r & 3) + 8 * (r >> 2) + 4 * h;
        ot[nr * 129 + cf * 32 + l31] = o[cfg][r] * lr[r];
      }
    }
    __syncthreads();
#pragma unroll 8
    for (int i = 0; i < 64; ++i) {
      const int cl = 2 * i + h;
      const float ov = ot[l31 * 129 + cl];
      const size_t gi =
          ((size_t)(b * NC + pass * 128 + cl)) * NNN + n0w + l31;
      out[gi] = gam * ov + x[gi];
    }
    __syncthreads();
  }
}

extern "C" void kernel_launch(void* const* d_in, const int* in_sizes, int n_in,
                              void* d_out, int out_size, void* d_ws,
                              size_t ws_size, hipStream_t stream) {
  const float* x = (const float*)d_in[0];
  const float* gamma = (const float*)d_in[1];
  float* out = (float*)d_out;
  ushort* fTs = (ushort*)d_ws;                         // 16.78 MB
  ushort* fVs = (ushort*)d_ws + (size_t)NB * NNN * NC; // + 16.78 MB

  dim3 pg(NNN / 32, NC / 32, NB);
  dim3 pb(32, 8, 1);
  prep_T<<<pg, pb, 0, stream>>>(x, fTs);
  prep_V<<<dim3(4096), dim3(256), 0, stream>>>(x, fVs);

  attn_kernel<<<dim3(256), dim3(256), 0, stream>>>(x, fTs, fVs, gamma, out);
}